// Round 8
// baseline (230.483 us; speedup 1.0000x reference)
//
#include <hip/hip_runtime.h>
#include <hip/hip_bf16.h>
#include <cmath>

typedef float f32x16 __attribute__((ext_vector_type(16)));
typedef __bf16 bf16x8 __attribute__((ext_vector_type(8)));
typedef __bf16 bf16x4 __attribute__((ext_vector_type(4)));

#define NE 8
#define H 1024
#define DF 2048
#define WCOLS 16384
#define NTOK 4096
#define MROWS 8192
#define NBLK 64

// Wt layout: 64 super-panels ep = e*8 + (256-col panel index). Element index:
//   (ep*32 + kb)*8192 + grp*1024 + chunk*256 + row*8 + j
//   global col = ep*256 + grp*32 + row ; k = kb*32 + chunk*8 + j
// Every 1KB = one wave-wide MFMA B fragment (32 cols x 8 k x 2 chunk-halves).
// GEMM reads B fragments DIRECTLY from global (L2-served, fully coalesced).

typedef const __attribute__((address_space(1))) unsigned int glb_u32;
typedef __attribute__((address_space(3))) unsigned int lds_u32;

__device__ __forceinline__ void async_load16(const void* g, void* l) {
    __builtin_amdgcn_global_load_lds((glb_u32*)g, (lds_u32*)l, 16, 0, 0);
}

// ---- prep: blocks [0,1024) = router (+ x->bf16); [1024,5120) = transpose ---
// (fused so router and transpose co-run; serial split cost ~10-14us, R4/R5)
__global__ __launch_bounds__(256) void prep_kernel(
    const float* __restrict__ x, const float* __restrict__ rw,
    const float* __restrict__ w1,
    float* __restrict__ logits, int* __restrict__ sel, float* __restrict__ rwn,
    __bf16* __restrict__ xb, __bf16* __restrict__ Wt)
{
    __shared__ float tile[32][132];
    int b = blockIdx.x;
    int tid = threadIdx.x;
    if (b < 1024) {
        // ---------------- router: 1 token per wave ----------------
        int tok  = b * 4 + (tid >> 6);
        int lane = tid & 63;
        const float* xr = x + (size_t)tok * H;
        __bf16* xbr = xb + (size_t)tok * H;
        float acc[NE];
#pragma unroll
        for (int e = 0; e < NE; ++e) acc[e] = 0.f;
#pragma unroll
        for (int it = 0; it < 4; ++it) {
            int k = (it * 64 + lane) * 4;
            float4 xv = *(const float4*)(xr + k);
            bf16x4 xc;
            xc[0] = (__bf16)xv.x; xc[1] = (__bf16)xv.y;
            xc[2] = (__bf16)xv.z; xc[3] = (__bf16)xv.w;
            *(bf16x4*)(xbr + k) = xc;
#pragma unroll
            for (int e = 0; e < NE; ++e) {
                float4 wv = *(const float4*)(rw + e * H + k);
                acc[e] += xv.x * wv.x + xv.y * wv.y + xv.z * wv.z + xv.w * wv.w;
            }
        }
#pragma unroll
        for (int e = 0; e < NE; ++e) {
            float v = acc[e];
#pragma unroll
            for (int off = 32; off > 0; off >>= 1) v += __shfl_xor(v, off, 64);
            acc[e] = v;
        }
        if (lane == 0) {
#pragma unroll
            for (int e = 0; e < NE; ++e) logits[tok * NE + e] = acc[e];
            int i1 = 0; float m1 = acc[0];
#pragma unroll
            for (int e = 1; e < NE; ++e) if (acc[e] > m1) { m1 = acc[e]; i1 = e; }
            int i2 = -1; float m2 = -INFINITY;
#pragma unroll
            for (int e = 0; e < NE; ++e) if (e != i1 && acc[e] > m2) { m2 = acc[e]; i2 = e; }
            float e2 = expf(m2 - m1);
            float inv = 1.f / (1.f + e2);
            sel[tok * 2]     = i1;  sel[tok * 2 + 1] = i2;
            rwn[tok * 2]     = inv; rwn[tok * 2 + 1] = e2 * inv;
        }
        return;
    }
    // -------- transpose into fragment-ordered Wt (coalesced, via LDS) -------
    int g  = b - 1024;                 // 0..4095
    int c  = g >> 5;                   // 128-col tile index, 0..127
    int kb = g & 31;
    int kk = tid >> 3;                 // 0..31
    int cc = (tid & 7) * 16;           // 0..112
    const float* src = w1 + (size_t)(kb * 32 + kk) * WCOLS + c * 128 + cc;
#pragma unroll
    for (int i = 0; i < 4; ++i) {
        float4 v = *(const float4*)(src + i * 4);
        *(float4*)&tile[kk][cc + i * 4] = v;
    }
    __syncthreads();
    int n = tid >> 1, kc0 = (tid & 1) * 16;
    bf16x8 o0, o1;
#pragma unroll
    for (int i = 0; i < 8; ++i) {
        o0[i] = (__bf16)tile[kc0 + i][n];       // k = kc0+i
        o1[i] = (__bf16)tile[kc0 + 8 + i][n];   // k = kc0+8+i
    }
    size_t tile_id = (size_t)(c >> 1) * 32 + kb;
    int group  = (c & 1) * 4 + (n >> 5);
    int chunk0 = kc0 >> 3;                       // 0 or 2
    __bf16* dst = Wt + tile_id * 8192 + group * 1024 + chunk0 * 256 + (n & 31) * 8;
    *(bf16x8*)dst         = o0;
    *(bf16x8*)(dst + 256) = o1;
}

// ------------- Stable counting sort by expert (1 block x 256) ---------------
__global__ __launch_bounds__(256) void sort_kernel(
    const int* __restrict__ sel, const float* __restrict__ rwn,
    int* __restrict__ stok, float* __restrict__ srw, int* __restrict__ bexp)
{
    __shared__ int cnt[NE][256];
    __shared__ int wtot[NE];
    __shared__ int ebase[NE + 1];
    int t = threadIdx.x;
    int selv[32];
    int lc[NE];
#pragma unroll
    for (int e = 0; e < NE; ++e) lc[e] = 0;
    int base = t * 32;
#pragma unroll
    for (int j = 0; j < 32; ++j) { selv[j] = sel[base + j]; lc[selv[j]]++; }
#pragma unroll
    for (int e = 0; e < NE; ++e) cnt[e][t] = lc[e];
    __syncthreads();
    // scan: wave w handles experts {2w, 2w+1}; lane l owns cnt[e][4l..4l+4)
    int l = t & 63;
#pragma unroll
    for (int ee = 0; ee < 2; ++ee) {
        int e = (t >> 6) * 2 + ee;
        int s = 0, pre[4];
#pragma unroll
        for (int i = 0; i < 4; ++i) { pre[i] = s; s += cnt[e][l * 4 + i]; }
        int inc = s;
#pragma unroll
        for (int d = 1; d < 64; d <<= 1) {
            int v = __shfl_up(inc, d, 64);
            if (l >= d) inc += v;
        }
        if (l == 63) wtot[e] = inc;
        int excl = inc - s;
#pragma unroll
        for (int i = 0; i < 4; ++i) cnt[e][l * 4 + i] = excl + pre[i];
    }
    __syncthreads();
    if (t == 0) {
        int acc = 0;
        for (int e = 0; e < NE; ++e) { ebase[e] = acc; acc += wtot[e]; }
        ebase[NE] = acc;
    }
    __syncthreads();
    int off[NE];
#pragma unroll
    for (int e = 0; e < NE; ++e) off[e] = ebase[e] + cnt[e][t];
#pragma unroll
    for (int j = 0; j < 32; ++j) {
        int i = base + j;
        int e = selv[j];
        int pos = off[e]++;
        stok[pos] = i >> 1;
        srw[pos]  = rwn[i];
    }
    __syncthreads();
    if (t < NBLK) {
        int r = t * 128;
        int e = 0;
        while (e < NE - 1 && r >= ebase[e + 1]) ++e;
        bexp[t] = e;
    }
}

// ---- kernel 3: GEMM. 1-WAVE blocks (64 thr), 64x64 tile, BK=32, ZERO
// ---- barriers. A: private 8KB LDS dbuf, gload_lds + counted vmcnt(4),
// ---- depth-2 (buffer freed by explicit lgkmcnt(0) after frag reads).
// ---- B: direct global fragment reads (1KB contiguous/wave), double-set regs.
// ---- Self-paced waves -> sync stall of the 2-barrier structure (m233: ~72%)
// ---- is gone; CU MFMA pipe oversubscribed ~4x by 12-16 independent waves.
__global__ __launch_bounds__(64) void moe_gemm(
    const __bf16* __restrict__ xb, const __bf16* __restrict__ Wt,
    const int* __restrict__ stok, const float* __restrict__ srw,
    const int* __restrict__ bexp, float* __restrict__ out)
{
    __shared__ __align__(16) __bf16 smem[2 * 2048];   // A only: 8KB

    int g  = blockIdx.x;                        // 4096 blocks
    int by = (g & 7) * 16 + ((g >> 3) & 15);    // 0..127: xcd-local A reuse
    int bx = g >> 7;                            // 0..31 (64-col panels)
    int lane = threadIdx.x;                     // single wave
    int l32  = lane & 31;
    int hi   = lane >> 5;
    int rdo  = hi * 256 + l32 * 8;

    int e    = bexp[by >> 1];
    int tok0 = stok[by * 64 + l32];
    int tok1 = stok[by * 64 + 32 + l32];
    const __bf16* aS0 = xb + (size_t)tok0 * H + hi * 8;
    const __bf16* aS1 = xb + (size_t)tok1 * H + hi * 8;
    const __bf16* bB  = Wt + (size_t)(e * 8 + (bx >> 2)) * 262144
                           + (size_t)((bx & 3) * 2) * 1024 + rdo;
    __bf16* aD = smem + lane * 8;               // per-lane = base + lane*16B

    f32x16 acc00, acc01, acc10, acc11;
#pragma unroll
    for (int r = 0; r < 16; ++r) { acc00[r] = 0.f; acc01[r] = 0.f;
                                   acc10[r] = 0.f; acc11[r] = 0.f; }

    bf16x8 bE[2][2], bO[2][2];                  // named B sets (rule #20)

    // prologue. Issue order matters for vmcnt counting: B(0) first, then A(0),
    // A(1) -> at t=0, vmcnt(4) leaves only A(1) in flight.
    bE[0][0] = *(const bf16x8*)(bB);
    bE[0][1] = *(const bf16x8*)(bB + 512);
    bE[1][0] = *(const bf16x8*)(bB + 1024);
    bE[1][1] = *(const bf16x8*)(bB + 1536);
    __builtin_amdgcn_sched_barrier(0);
    async_load16(aS0,      aD);          async_load16(aS0 + 16, aD + 512);
    async_load16(aS1,      aD + 1024);   async_load16(aS1 + 16, aD + 1536);
    async_load16(aS0 + 32, aD + 2048);   async_load16(aS0 + 48, aD + 2560);
    async_load16(aS1 + 32, aD + 3072);   async_load16(aS1 + 48, aD + 3584);

    // Per iter t: vmcnt(4) -> A(t) LDS-resident (everything older than the 4
    // newest VMEM ops is complete; A(t+1) batch stays in flight). ds_read the
    // 4 A fragments; lgkmcnt(0) frees buffer t&1; load B(t+1) regs; restage
    // A(t+2) into the freed buffer; 8 MFMA on B(t). No barriers anywhere.
#define ITER(t_, bC_, bN_, DOB_, DOA_, VN_) do {                               \
    asm volatile("s_waitcnt vmcnt(" #VN_ ")" ::: "memory");                    \
    __builtin_amdgcn_sched_barrier(0);                                         \
    const __bf16* Ab_ = smem + ((t_) & 1) * 2048;                              \
    bf16x8 af00 = *(const bf16x8*)(Ab_ + rdo);                                 \
    bf16x8 af01 = *(const bf16x8*)(Ab_ + rdo + 512);                           \
    bf16x8 af10 = *(const bf16x8*)(Ab_ + rdo + 1024);                          \
    bf16x8 af11 = *(const bf16x8*)(Ab_ + rdo + 1536);                          \
    asm volatile("s_waitcnt lgkmcnt(0)" ::: "memory");                         \
    __builtin_amdgcn_sched_barrier(0);                                         \
    if (DOB_) {                                                                \
        const __bf16* bp_ = bB + (size_t)((t_) + 1) * 8192;                    \
        bN_[0][0] = *(const bf16x8*)(bp_);                                     \
        bN_[0][1] = *(const bf16x8*)(bp_ + 512);                               \
        bN_[1][0] = *(const bf16x8*)(bp_ + 1024);                              \
        bN_[1][1] = *(const bf16x8*)(bp_ + 1536);                              \
    }                                                                          \
    __builtin_amdgcn_sched_barrier(0);                                         \
    if (DOA_) {                                                                \
        const __bf16* a0_ = aS0 + ((t_) + 2) * 32;                             \
        const __bf16* a1_ = aS1 + ((t_) + 2) * 32;                             \
        __bf16* ad_ = aD + ((t_) & 1) * 2048;                                  \
        async_load16(a0_,      ad_);        async_load16(a0_ + 16, ad_ + 512); \
        async_load16(a1_,      ad_ + 1024); async_load16(a1_ + 16, ad_ + 1536);\
    }                                                                          \
    __builtin_amdgcn_s_setprio(1);                                             \
    acc00 = __builtin_amdgcn_mfma_f32_32x32x16_bf16(af00, bC_[0][0], acc00, 0, 0, 0); \
    acc01 = __builtin_amdgcn_mfma_f32_32x32x16_bf16(af00, bC_[1][0], acc01, 0, 0, 0); \
    acc10 = __builtin_amdgcn_mfma_f32_32x32x16_bf16(af10, bC_[0][0], acc10, 0, 0, 0); \
    acc11 = __builtin_amdgcn_mfma_f32_32x32x16_bf16(af10, bC_[1][0], acc11, 0, 0, 0); \
    acc00 = __builtin_amdgcn_mfma_f32_32x32x16_bf16(af01, bC_[0][1], acc00, 0, 0, 0); \
    acc01 = __builtin_amdgcn_mfma_f32_32x32x16_bf16(af01, bC_[1][1], acc01, 0, 0, 0); \
    acc10 = __builtin_amdgcn_mfma_f32_32x32x16_bf16(af11, bC_[0][1], acc10, 0, 0, 0); \
    acc11 = __builtin_amdgcn_mfma_f32_32x32x16_bf16(af11, bC_[1][1], acc11, 0, 0, 0); \
    __builtin_amdgcn_s_setprio(0);                                             \
} while (0)

    for (int kt = 0; kt < 30; kt += 2) {
        ITER(kt,     bE, bO, 1, 1, 4);
        ITER(kt + 1, bO, bE, 1, 1, 4);
    }
    ITER(30, bE, bO, 1, 0, 4);
    ITER(31, bO, bE, 0, 0, 0);
#undef ITER

    // epilogue: gelu (tanh form) * rw; C/D: row=(reg&3)+8*(reg>>2)+4*hi, col=l32
    const float* rwp = srw + by * 64;
    float* outp = out + (size_t)(by * 64) * DF + (size_t)bx * 64 + l32;
#define EPI(ACC_, ti_, tj_) _Pragma("unroll")                                  \
    for (int reg = 0; reg < 16; ++reg) {                                       \
        int row = (reg & 3) + 8 * (reg >> 2) + 4 * hi + (ti_) * 32;            \
        float val = ACC_[reg];                                                 \
        float u = 0.7978845608028654f * val * (1.f + 0.044715f * val * val);   \
        float t = __expf(-2.f * fabsf(u));                                     \
        float th = (1.f - t) / (1.f + t);                                      \
        th = u < 0.f ? -th : th;                                               \
        outp[(size_t)row * DF + (tj_) * 32] = 0.5f * val * (1.f + th) * rwp[row]; \
    }
    EPI(acc00, 0, 0)
    EPI(acc01, 0, 1)
    EPI(acc10, 1, 0)
    EPI(acc11, 1, 1)
#undef EPI
}

extern "C" void kernel_launch(void* const* d_in, const int* in_sizes, int n_in,
                              void* d_out, int out_size, void* d_ws, size_t ws_size,
                              hipStream_t stream) {
    (void)in_sizes; (void)n_in; (void)out_size; (void)ws_size;
    const float* x        = (const float*)d_in[0];
    const float* router_w = (const float*)d_in[1];
    const float* w1       = (const float*)d_in[2];
    float* out    = (float*)d_out;
    float* logits = out + (size_t)MROWS * DF;

    char* ws    = (char*)d_ws;
    int*   sel  = (int*)(ws);
    float* rwn  = (float*)(ws + 0x8000);
    int*   stok = (int*)(ws + 0x10000);
    float* srw  = (float*)(ws + 0x18000);
    int*   bexp = (int*)(ws + 0x20000);
    __bf16* xb  = (__bf16*)(ws + (1 << 20));             // 8 MB
    __bf16* Wt  = (__bf16*)(ws + (1 << 20) + (8 << 20)); // 32 MB

    prep_kernel<<<5120, 256, 0, stream>>>(x, router_w, w1, logits, sel, rwn, xb, Wt);
    sort_kernel<<<1, 256, 0, stream>>>(sel, rwn, stok, srw, bexp);
    moe_gemm<<<4096, 64, 0, stream>>>(xb, Wt, stok, srw, bexp, out);
}

// Round 9
// 195.049 us; speedup vs baseline: 1.1817x; 1.1817x over previous
//
#include <hip/hip_runtime.h>
#include <hip/hip_bf16.h>
#include <cmath>

typedef float f32x16 __attribute__((ext_vector_type(16)));
typedef __bf16 bf16x8 __attribute__((ext_vector_type(8)));
typedef __bf16 bf16x4 __attribute__((ext_vector_type(4)));

#define NE 8
#define H 1024
#define DF 2048
#define WCOLS 16384
#define NTOK 4096
#define MROWS 8192
#define NBLK 64

// Wt layout: 64 super-panels ep = e*8 + (256-col panel index). Element index:
//   (ep*32 + kb)*8192 + grp*1024 + chunk*256 + row*8 + j
//   global col = ep*256 + grp*32 + row ; k = kb*32 + chunk*8 + j
// Every 16B = 8 k-consecutive elems of one w1 column (exact MFMA B fragment).
// GEMM stages tiles as LINEAR global_load_lds copies; fragment reads are
// 1KB-contiguous per wave -> zero bank conflicts (verified R1/R4/R6/R7: 0).

typedef const __attribute__((address_space(1))) unsigned int glb_u32;
typedef __attribute__((address_space(3))) unsigned int lds_u32;

__device__ __forceinline__ void async_load16(const void* g, void* l) {
    __builtin_amdgcn_global_load_lds((glb_u32*)g, (lds_u32*)l, 16, 0, 0);
}

// ---------------- kernel 1: router + x->bf16 (1024 blocks) ------------------
__global__ __launch_bounds__(256) void router_kernel(
    const float* __restrict__ x, const float* __restrict__ rw,
    float* __restrict__ logits, int* __restrict__ sel, float* __restrict__ rwn,
    __bf16* __restrict__ xb)
{
    int b = blockIdx.x;
    int tid = threadIdx.x;
    int tok  = b * 4 + (tid >> 6);
    int lane = tid & 63;
    const float* xr = x + (size_t)tok * H;
    __bf16* xbr = xb + (size_t)tok * H;
    float acc[NE];
#pragma unroll
    for (int e = 0; e < NE; ++e) acc[e] = 0.f;
#pragma unroll
    for (int it = 0; it < 4; ++it) {
        int k = (it * 64 + lane) * 4;
        float4 xv = *(const float4*)(xr + k);
        bf16x4 xc;
        xc[0] = (__bf16)xv.x; xc[1] = (__bf16)xv.y;
        xc[2] = (__bf16)xv.z; xc[3] = (__bf16)xv.w;
        *(bf16x4*)(xbr + k) = xc;
#pragma unroll
        for (int e = 0; e < NE; ++e) {
            float4 wv = *(const float4*)(rw + e * H + k);
            acc[e] += xv.x * wv.x + xv.y * wv.y + xv.z * wv.z + xv.w * wv.w;
        }
    }
#pragma unroll
    for (int e = 0; e < NE; ++e) {
        float v = acc[e];
#pragma unroll
        for (int off = 32; off > 0; off >>= 1) v += __shfl_xor(v, off, 64);
        acc[e] = v;
    }
    if (lane == 0) {
#pragma unroll
        for (int e = 0; e < NE; ++e) logits[tok * NE + e] = acc[e];
        int i1 = 0; float m1 = acc[0];
#pragma unroll
        for (int e = 1; e < NE; ++e) if (acc[e] > m1) { m1 = acc[e]; i1 = e; }
        int i2 = -1; float m2 = -INFINITY;
#pragma unroll
        for (int e = 0; e < NE; ++e) if (e != i1 && acc[e] > m2) { m2 = acc[e]; i2 = e; }
        float e2 = expf(m2 - m1);
        float inv = 1.f / (1.f + e2);
        sel[tok * 2]     = i1;  sel[tok * 2 + 1] = i2;
        rwn[tok * 2]     = inv; rwn[tok * 2 + 1] = e2 * inv;
    }
}

// ------ kernel 2: blocks [0,4096) = coalesced LDS-transpose of w1 -> Wt;
// ------           block 4096 = counting sort (concurrent -> fully hidden) ---
__global__ __launch_bounds__(256) void mid_kernel(
    const float* __restrict__ w1, __bf16* __restrict__ Wt,
    const int* __restrict__ sel, const float* __restrict__ rwn,
    int* __restrict__ stok, float* __restrict__ srw, int* __restrict__ bexp)
{
    __shared__ float tile[32][132];
    __shared__ int cnt[NE][256];
    __shared__ int wtot[NE];
    __shared__ int ebase[NE + 1];
    int b = blockIdx.x;
    int t = threadIdx.x;

    if (b < 4096) {
        // coalesced float4 row reads (nontemporal: read-once, don't evict Wt)
        int c  = b >> 5;                   // 128-col tile index, 0..127
        int kb = b & 31;
        int kk = t >> 3;                   // 0..31
        int cc = (t & 7) * 16;             // 0..112
        const float* src = w1 + (size_t)(kb * 32 + kk) * WCOLS + c * 128 + cc;
#pragma unroll
        for (int i = 0; i < 4; ++i) {
            float4 v;
            v.x = __builtin_nontemporal_load(src + i * 4);
            v.y = __builtin_nontemporal_load(src + i * 4 + 1);
            v.z = __builtin_nontemporal_load(src + i * 4 + 2);
            v.w = __builtin_nontemporal_load(src + i * 4 + 3);
            *(float4*)&tile[kk][cc + i * 4] = v;
        }
        __syncthreads();
        int n = t >> 1, kc0 = (t & 1) * 16;
        bf16x8 o0, o1;
#pragma unroll
        for (int i = 0; i < 8; ++i) {
            o0[i] = (__bf16)tile[kc0 + i][n];       // k = kc0+i
            o1[i] = (__bf16)tile[kc0 + 8 + i][n];   // k = kc0+8+i
        }
        size_t tile_id = (size_t)(c >> 1) * 32 + kb;
        int group  = (c & 1) * 4 + (n >> 5);
        int chunk0 = kc0 >> 3;                       // 0 or 2
        __bf16* dst = Wt + tile_id * 8192 + group * 1024 + chunk0 * 256 + (n & 31) * 8;
        *(bf16x8*)dst         = o0;
        *(bf16x8*)(dst + 256) = o1;
        return;
    }

    // ---------------- sort: 256 threads, 32 items each (hidden) -------------
    int selv[32];
    int lc[NE];
#pragma unroll
    for (int e = 0; e < NE; ++e) lc[e] = 0;
    int base = t * 32;
#pragma unroll
    for (int j = 0; j < 32; ++j) { selv[j] = sel[base + j]; lc[selv[j]]++; }
#pragma unroll
    for (int e = 0; e < NE; ++e) cnt[e][t] = lc[e];
    __syncthreads();
    // scan: wave w handles experts {2w, 2w+1}; lane l owns cnt[e][4l..4l+4)
    int l = t & 63;
#pragma unroll
    for (int ee = 0; ee < 2; ++ee) {
        int e = (t >> 6) * 2 + ee;
        int s = 0, pre[4];
#pragma unroll
        for (int i = 0; i < 4; ++i) { pre[i] = s; s += cnt[e][l * 4 + i]; }
        int inc = s;
#pragma unroll
        for (int d = 1; d < 64; d <<= 1) {
            int v = __shfl_up(inc, d, 64);
            if (l >= d) inc += v;
        }
        if (l == 63) wtot[e] = inc;
        int excl = inc - s;
#pragma unroll
        for (int i = 0; i < 4; ++i) cnt[e][l * 4 + i] = excl + pre[i];
    }
    __syncthreads();
    if (t == 0) {
        int acc = 0;
        for (int e = 0; e < NE; ++e) { ebase[e] = acc; acc += wtot[e]; }
        ebase[NE] = acc;
    }
    __syncthreads();
    int off[NE];
#pragma unroll
    for (int e = 0; e < NE; ++e) off[e] = ebase[e] + cnt[e][t];
#pragma unroll
    for (int j = 0; j < 32; ++j) {
        int i = base + j;
        int e = selv[j];
        int pos = off[e]++;
        stok[pos] = i >> 1;
        srw[pos]  = rwn[i];
    }
    __syncthreads();
    if (t < NBLK) {
        int r = t * 128;
        int e = 0;
        while (e < NE - 1 && r >= ebase[e + 1]) ++e;
        bexp[t] = e;
    }
}

// ---- kernel 3: GEMM (R7's proven config). 128x128 tile, 4 waves x (64x64),
// ---- BK=32, 2x16KB dbuf (33KB -> 4 blocks/CU), drain schedule, conflict-free
// ---- fragment LDS. Only change vs R7: nontemporal out-stores (keep Wt/xb in L2).
__global__ __launch_bounds__(256, 4) void moe_gemm(
    const __bf16* __restrict__ xb, const __bf16* __restrict__ Wt,
    const int* __restrict__ stok, const float* __restrict__ srw,
    const int* __restrict__ bexp, float* __restrict__ out)
{
    // buffer bb (8192 elems = 16KB): A [0,4096) = [grp4][chunk4][row32][8]
    //                                B [4096,8192) = [grp4][chunk4][row32][8]
    __shared__ __align__(16) __bf16 smem[2 * 8192];   // 32KB -> 4 blocks/CU
    __shared__ int   tokS[128];
    __shared__ float rwS[128];

    int g = blockIdx.x;                        // 1024 blocks
    int by = (g & 7) * 8 + ((g >> 3) & 7);     // 0..63 (XCD swizzle)
    int bx = g >> 6;                           // 0..15 (128-col tiles)
    int tid = threadIdx.x;
    if (tid < 128) {
        tokS[tid] = stok[by * 128 + tid];
        rwS[tid]  = srw[by * 128 + tid];
    }
    int e = bexp[by];
    __syncthreads();

    int lane = tid & 63;
    int wv   = tid >> 6;
    int l32  = lane & 31;
    int hi   = lane >> 5;

    // A staging: virtual slot v in [0,512): grp=v>>7, chunk=(v>>5)&3, row=v&31
    int g0 = tid >> 7, c0_ = (tid >> 5) & 3, r0_ = tid & 31;       // v = tid
    int g1 = (tid + 256) >> 7, c1_ = ((tid + 256) >> 5) & 3;       // v = tid+256
    const __bf16* aSrc0 = xb + (size_t)tokS[g0 * 32 + r0_] * H + c0_ * 8;
    const __bf16* aSrc1 = xb + (size_t)tokS[g1 * 32 + r0_] * H + c1_ * 8;
    // B staging: linear 8KB copy per K-tile from fragment-ordered Wt
    const __bf16* bSrcT = Wt + (size_t)(e * 8 + (bx >> 1)) * 262144
                             + (bx & 1) * 4096 + tid * 8;
    __bf16* aDstT = smem + tid * 8;            // + j*4KB for v=tid+256j
    __bf16* bDstT = smem + 4096 + tid * 8;

#define STAGE(kt_, bb_) do {                                                   \
        __bf16* ad_ = aDstT + (bb_) * 8192;                                    \
        async_load16(aSrc0 + (kt_) * 32, ad_);                                 \
        async_load16(aSrc1 + (kt_) * 32, ad_ + 2048);                          \
        const __bf16* b_ = bSrcT + (size_t)(kt_) * 8192;                       \
        __bf16* bd_ = bDstT + (bb_) * 8192;                                    \
        async_load16(b_,        bd_);                                          \
        async_load16(b_ + 2048, bd_ + 2048);                                   \
    } while (0)

    int wm  = (wv & 1) * 64;
    int wn  = (wv >> 1) * 64;
    int agb = (wv & 1) * 2;                    // A group base
    int bgb = (wv >> 1) * 2;                   // B group base
    int rdo = hi * 256 + l32 * 8;              // chunk-parity + lane offset

    f32x16 acc[2][2];
#pragma unroll
    for (int i = 0; i < 2; ++i)
#pragma unroll
        for (int j = 0; j < 2; ++j)
#pragma unroll
            for (int r = 0; r < 16; ++r) acc[i][j][r] = 0.f;

    // prologue: stage K-tile 0 into buffer 0
    STAGE(0, 0);

    for (int kt = 0; kt < 32; ++kt) {
        int cur = kt & 1;
        __syncthreads();               // drains vmcnt: buffer cur ready; also
                                       // orders reuse of the other buffer
        if (kt < 31) STAGE(kt + 1, 1 - cur);

        const __bf16* Ab = smem + cur * 8192;
        bf16x8 af[2][2], bfr[2][2];
#pragma unroll
        for (int h = 0; h < 2; ++h) {
            int co = h * 512 + rdo;            // chunk = h*2 + hi
#pragma unroll
            for (int ti = 0; ti < 2; ++ti)
                af[ti][h]  = *(const bf16x8*)&Ab[(agb + ti) * 1024 + co];
#pragma unroll
            for (int tj = 0; tj < 2; ++tj)
                bfr[tj][h] = *(const bf16x8*)&Ab[4096 + (bgb + tj) * 1024 + co];
        }
#pragma unroll
        for (int h = 0; h < 2; ++h)
#pragma unroll
            for (int ti = 0; ti < 2; ++ti)
#pragma unroll
                for (int tj = 0; tj < 2; ++tj)
                    acc[ti][tj] = __builtin_amdgcn_mfma_f32_32x32x16_bf16(
                        af[ti][h], bfr[tj][h], acc[ti][tj], 0, 0, 0);
    }
#undef STAGE

    // epilogue: gelu (tanh form) * rw; C/D: row=(reg&3)+8*(reg>>2)+4*hi, col=l32
    int rowh = hi * 4;
#pragma unroll
    for (int ti = 0; ti < 2; ++ti)
#pragma unroll
        for (int reg = 0; reg < 16; ++reg) {
            int row = (reg & 3) + 8 * (reg >> 2) + rowh;
            int m = wm + ti * 32 + row;
            float rw = rwS[m];
            size_t ob = (size_t)(by * 128 + m) * DF + bx * 128 + wn + l32;
#pragma unroll
            for (int tj = 0; tj < 2; ++tj) {
                float val = acc[ti][tj][reg];
                float u = 0.7978845608028654f * val * (1.f + 0.044715f * val * val);
                float t = __expf(-2.f * fabsf(u));
                float th = (1.f - t) / (1.f + t);
                th = u < 0.f ? -th : th;
                __builtin_nontemporal_store(0.5f * val * (1.f + th) * rw,
                                            &out[ob + tj * 32]);
            }
        }
}

extern "C" void kernel_launch(void* const* d_in, const int* in_sizes, int n_in,
                              void* d_out, int out_size, void* d_ws, size_t ws_size,
                              hipStream_t stream) {
    (void)in_sizes; (void)n_in; (void)out_size; (void)ws_size;
    const float* x        = (const float*)d_in[0];
    const float* router_w = (const float*)d_in[1];
    const float* w1       = (const float*)d_in[2];
    float* out    = (float*)d_out;
    float* logits = out + (size_t)MROWS * DF;

    char* ws    = (char*)d_ws;
    int*   sel  = (int*)(ws);
    float* rwn  = (float*)(ws + 0x8000);
    int*   stok = (int*)(ws + 0x10000);
    float* srw  = (float*)(ws + 0x18000);
    int*   bexp = (int*)(ws + 0x20000);
    __bf16* xb  = (__bf16*)(ws + (1 << 20));             // 8 MB
    __bf16* Wt  = (__bf16*)(ws + (1 << 20) + (8 << 20)); // 32 MB

    router_kernel<<<1024, 256, 0, stream>>>(x, router_w, logits, sel, rwn, xb);
    mid_kernel<<<4097, 256, 0, stream>>>(w1, Wt, sel, rwn, stok, srw, bexp);
    moe_gemm<<<1024, 256, 0, stream>>>(xb, Wt, stok, srw, bexp, out);
}